// Round 1
// baseline (51.999 us; speedup 1.0000x reference)
//
#include <hip/hip_runtime.h>

#define N_NODES 4096
#define IN_DIM  128
#define OUT_DIM 32
#define HEADS   4
#define FDIM    128   // OUT_DIM*HEADS

// ---------------- Kernel 1: xp = x@W ; s_i, s_j per (row, head) ----------------
// One block of 128 threads per row. W streamed coalesced (64 KB, L2-resident).
__global__ __launch_bounds__(128) void gat_proj(const float* __restrict__ x,
                                                const float* __restrict__ W,
                                                const float* __restrict__ a,
                                                float* __restrict__ xp,
                                                float* __restrict__ sI,
                                                float* __restrict__ sJ) {
    const int row = blockIdx.x;
    const int t   = threadIdx.x;          // output column = h*32 + d
    __shared__ float xs[IN_DIM];
    xs[t] = x[row * IN_DIM + t];
    __syncthreads();

    float acc = 0.f;
#pragma unroll
    for (int k = 0; k < IN_DIM; ++k)
        acc = fmaf(xs[k], W[k * FDIM + t], acc);
    xp[row * FDIM + t] = acc;

    const int d = t & 31;
    float vj = acc * a[d];            // a_j = a[:32]
    float vi = acc * a[OUT_DIM + d];  // a_i = a[32:]
#pragma unroll
    for (int off = 16; off > 0; off >>= 1) {
        vi += __shfl_down(vi, off, 32);
        vj += __shfl_down(vj, off, 32);
    }
    if (d == 0) {
        const int h = t >> 5;
        sI[row * HEADS + h] = vi;
        sJ[row * HEADS + h] = vj;
    }
}

// ---------------- Kernel 2: fused masked softmax + aggregate ----------------
// One block (256 threads = 4 waves) per row i. Wave w handles head w.
__global__ __launch_bounds__(256) void gat_agg(const float* __restrict__ adj,
                                               const float* __restrict__ xp,
                                               const float* __restrict__ sI,
                                               const float* __restrict__ sJ,
                                               float* __restrict__ out) {
    const int i   = blockIdx.x;
    const int tid = threadIdx.x;

    __shared__ int elist[N_NODES];   // 16 KB — worst-case capacity, always correct
    __shared__ int cnt[256];
    __shared__ int s_nE;

    // ---- Phase A: scan adj row (coalesced float4), count nonzeros ----
    const float4* arow = (const float4*)(adj + (size_t)i * N_NODES);
    float4 v[4];
#pragma unroll
    for (int k = 0; k < 4; ++k) v[k] = arow[tid + 256 * k];
    int mycnt = 0;
#pragma unroll
    for (int k = 0; k < 4; ++k)
        mycnt += (v[k].x != 0.f) + (v[k].y != 0.f) + (v[k].z != 0.f) + (v[k].w != 0.f);
    cnt[tid] = mycnt;
    __syncthreads();

    // ---- Phase B: inclusive Hillis-Steele scan over 256 counts ----
    for (int off = 1; off < 256; off <<= 1) {
        int add = (tid >= off) ? cnt[tid - off] : 0;
        __syncthreads();
        cnt[tid] += add;
        __syncthreads();
    }
    int wpos = cnt[tid] - mycnt;   // exclusive offset — deterministic compaction

    // ---- Phase C: write compacted edge indices ----
#pragma unroll
    for (int k = 0; k < 4; ++k) {
        const int jbase = (tid + 256 * k) * 4;
        float vals[4] = {v[k].x, v[k].y, v[k].z, v[k].w};
#pragma unroll
        for (int m = 0; m < 4; ++m)
            if (vals[m] != 0.f) elist[wpos++] = jbase + m;
    }
    if (tid == 255) s_nE = cnt[255];
    __syncthreads();
    const int nE = s_nE;   // >= 1 (diagonal)

    // ---- Phase D: per-head online softmax stats (wave w = head w) ----
    const int h    = tid >> 6;
    const int lane = tid & 63;
    const float scale = 0.17677669529663687f;   // 1/sqrt(32)
    const float si = sI[i * HEADS + h];

    float m = -1e30f, Z = 0.f;
    for (int e = lane; e < nE; e += 64) {
        const int j = elist[e];
        const float ej = (si + sJ[j * HEADS + h]) * scale;
        if (ej > m) { Z *= __expf(m - ej); m = ej; }
        Z += __expf(ej - m);
    }
#pragma unroll
    for (int off = 32; off > 0; off >>= 1) {
        const float m2 = __shfl_xor(m, off);
        const float Z2 = __shfl_xor(Z, off);
        const float mn = fmaxf(m, m2);
        Z = Z * __expf(m - mn) + Z2 * __expf(m2 - mn);
        m = mn;
    }
    // all 64 lanes now hold the head's (m, Z)

    // ---- Phase E: weighted aggregation. half-wave per edge-parity, lane = dim ----
    const int d    = lane & 31;
    const int half = lane >> 5;
    float acc = 0.f;
    for (int e = half; e < nE; e += 2) {
        const int j = elist[e];
        const float p = __expf((si + sJ[j * HEADS + h]) * scale - m);
        acc = fmaf(p, xp[j * FDIM + h * OUT_DIM + d], acc);
    }
    acc += __shfl_down(acc, 32);   // combine the two halves
    if (lane < 32)
        out[i * FDIM + h * OUT_DIM + d] = acc / Z;
}

extern "C" void kernel_launch(void* const* d_in, const int* in_sizes, int n_in,
                              void* d_out, int out_size, void* d_ws, size_t ws_size,
                              hipStream_t stream) {
    const float* x   = (const float*)d_in[0];
    const float* adj = (const float*)d_in[1];
    const float* W   = (const float*)d_in[2];
    const float* a   = (const float*)d_in[3];
    float* out = (float*)d_out;

    float* xp = (float*)d_ws;                    // 4096*128 f32 = 2 MB
    float* sI = xp + N_NODES * FDIM;             // 64 KB
    float* sJ = sI + N_NODES * HEADS;            // 64 KB

    gat_proj<<<N_NODES, 128, 0, stream>>>(x, W, a, xp, sI, sJ);
    gat_agg<<<N_NODES, 256, 0, stream>>>(adj, xp, sI, sJ, out);
}

// Round 2
// 35.021 us; speedup vs baseline: 1.4848x; 1.4848x over previous
//
#include <hip/hip_runtime.h>

#define N_NODES 4096
#define IN_DIM  128
#define OUT_DIM 32
#define HEADS   4
#define FDIM    128   // OUT_DIM*HEADS
#define K1_ROWS 8

// ---------------- Kernel 1: xp = x@W ; s_i, s_j per (row, head) ----------------
// 8 rows per block (256 threads): W read once per 8 rows -> 32 MB L2 total.
__global__ __launch_bounds__(256) void gat_proj(const float* __restrict__ x,
                                                const float* __restrict__ W,
                                                const float* __restrict__ a,
                                                float* __restrict__ xp,
                                                float* __restrict__ sI,
                                                float* __restrict__ sJ) {
    __shared__ float xs[K1_ROWS * IN_DIM];   // 4 KB: x tile, then reused as xp tile
    const int t    = threadIdx.x;
    const int row0 = blockIdx.x * K1_ROWS;

    ((float4*)xs)[t] = ((const float4*)(x + (size_t)row0 * IN_DIM))[t];
    __syncthreads();

    const int c  = t & 127;          // output column
    const int rg = t >> 7;           // 0..1 -> rows rg*4 .. rg*4+3
    const float* xb = xs + (rg * 4) * IN_DIM;

    float acc0 = 0.f, acc1 = 0.f, acc2 = 0.f, acc3 = 0.f;
#pragma unroll 4
    for (int k0 = 0; k0 < IN_DIM; k0 += 4) {
        const float w0 = W[(k0 + 0) * FDIM + c];
        const float w1 = W[(k0 + 1) * FDIM + c];
        const float w2 = W[(k0 + 2) * FDIM + c];
        const float w3 = W[(k0 + 3) * FDIM + c];
        const float4 x0 = *(const float4*)(xb + 0 * IN_DIM + k0);
        const float4 x1 = *(const float4*)(xb + 1 * IN_DIM + k0);
        const float4 x2 = *(const float4*)(xb + 2 * IN_DIM + k0);
        const float4 x3 = *(const float4*)(xb + 3 * IN_DIM + k0);
        acc0 = fmaf(x0.x, w0, fmaf(x0.y, w1, fmaf(x0.z, w2, fmaf(x0.w, w3, acc0))));
        acc1 = fmaf(x1.x, w0, fmaf(x1.y, w1, fmaf(x1.z, w2, fmaf(x1.w, w3, acc1))));
        acc2 = fmaf(x2.x, w0, fmaf(x2.y, w1, fmaf(x2.z, w2, fmaf(x2.w, w3, acc2))));
        acc3 = fmaf(x3.x, w0, fmaf(x3.y, w1, fmaf(x3.z, w2, fmaf(x3.w, w3, acc3))));
    }

    const int rb = rg * 4;
    xp[(size_t)(row0 + rb + 0) * FDIM + c] = acc0;
    xp[(size_t)(row0 + rb + 1) * FDIM + c] = acc1;
    xp[(size_t)(row0 + rb + 2) * FDIM + c] = acc2;
    xp[(size_t)(row0 + rb + 3) * FDIM + c] = acc3;

    __syncthreads();                      // everyone done reading x tile
    xs[(rb + 0) * FDIM + c] = acc0;       // reuse LDS as xp tile
    xs[(rb + 1) * FDIM + c] = acc1;
    xs[(rb + 2) * FDIM + c] = acc2;
    xs[(rb + 3) * FDIM + c] = acc3;
    __syncthreads();

    if (t < K1_ROWS * HEADS) {            // 32 threads: (row, head) pairs
        const int r = t >> 2, h = t & 3;
        const float4* xr = (const float4*)(xs + r * FDIM + h * OUT_DIM);
        const float4* aj = (const float4*)a;             // a[:32]
        const float4* ai = (const float4*)(a + OUT_DIM); // a[32:]
        float vi = 0.f, vj = 0.f;
#pragma unroll
        for (int q = 0; q < 8; ++q) {
            const float4 xv = xr[q], a1 = ai[q], a0 = aj[q];
            vi += xv.x * a1.x + xv.y * a1.y + xv.z * a1.z + xv.w * a1.w;
            vj += xv.x * a0.x + xv.y * a0.y + xv.z * a0.z + xv.w * a0.w;
        }
        sI[(row0 + r) * HEADS + h] = vi;
        sJ[(row0 + r) * HEADS + h] = vj;
    }
}

// ---------------- Kernel 2: fused scan + masked softmax + aggregate ----------------
// One block (4 waves) per row i. Wave w scans quarter w (ballot compaction,
// no barriers); after ONE barrier, wave h = head h does softmax + float4 agg.
__global__ __launch_bounds__(256) void gat_agg(const float* __restrict__ adj,
                                               const float* __restrict__ xp,
                                               const float* __restrict__ sI,
                                               const float* __restrict__ sJ,
                                               float* __restrict__ out) {
    const int i    = blockIdx.x;
    const int tid  = threadIdx.x;
    const int wv   = tid >> 6;
    const int lane = tid & 63;

    __shared__ int elist[HEADS][1024];   // 16 KB, exact worst-case per quarter
    __shared__ int cnts[HEADS];

    // ---- Phase A: wave-local scan of quarter wv, all 4 KB issued up front ----
    const float4* arow = (const float4*)(adj + (size_t)i * N_NODES) + wv * 256;
    const float4 v0 = arow[lane];
    const float4 v1 = arow[64 + lane];
    const float4 v2 = arow[128 + lane];
    const float4 v3 = arow[192 + lane];

    const unsigned long long lt = (1ULL << lane) - 1ULL;
    int* segp = elist[wv];
    int base = 0;
    const int cb = wv * 1024 + lane * 4;

#define COMPACT(val, col)                                                     \
    {                                                                         \
        const unsigned long long mk = __ballot((val) != 0.f);                 \
        if ((val) != 0.f) segp[base + __popcll(mk & lt)] = (col);             \
        base += __popcll(mk);                                                 \
    }
    COMPACT(v0.x, cb + 0)   COMPACT(v0.y, cb + 1)   COMPACT(v0.z, cb + 2)   COMPACT(v0.w, cb + 3)
    COMPACT(v1.x, cb + 256) COMPACT(v1.y, cb + 257) COMPACT(v1.z, cb + 258) COMPACT(v1.w, cb + 259)
    COMPACT(v2.x, cb + 512) COMPACT(v2.y, cb + 513) COMPACT(v2.z, cb + 514) COMPACT(v2.w, cb + 515)
    COMPACT(v3.x, cb + 768) COMPACT(v3.y, cb + 769) COMPACT(v3.z, cb + 770) COMPACT(v3.w, cb + 771)
#undef COMPACT

    if (lane == 0) cnts[wv] = base;
    __syncthreads();

    const int c0 = cnts[0], c1 = cnts[1], c2 = cnts[2];
    const int o1 = c0, o2 = c0 + c1, o3 = c0 + c1 + c2;
    const int nE = o3 + cnts[3];

    const int h = wv;
    const float scale = 0.17677669529663687f;   // 1/sqrt(32)
    const float si = sI[i * HEADS + h];

    // ---- Phase B: online softmax stats, edges across all 64 lanes ----
    float m = -1e30f, Z = 0.f;
    for (int e = lane; e < nE; e += 64) {
        const int s3 = e >= o3, s2 = e >= o2, s1 = e >= o1;
        const int sg = s1 + s2 + s3;
        const int sub = e - (s3 ? o3 : (s2 ? o2 : (s1 ? o1 : 0)));
        const int j = elist[sg][sub];
        const float ej = (si + sJ[j * HEADS + h]) * scale;
        const float mn = fmaxf(m, ej);
        Z = Z * __expf(m - mn) + __expf(ej - mn);
        m = mn;
    }
#pragma unroll
    for (int off = 32; off; off >>= 1) {
        const float m2 = __shfl_xor(m, off);
        const float Z2 = __shfl_xor(Z, off);
        const float mn = fmaxf(m, m2);
        Z = Z * __expf(m - mn) + Z2 * __expf(m2 - mn);
        m = mn;
    }

    // ---- Phase C: float4 aggregation: lane = (edge-slot eg, dim-group d4) ----
    const int d4 = lane & 7, eg = lane >> 3;
    float ax = 0.f, ay = 0.f, az = 0.f, aw = 0.f;
    const float4* xp4 = (const float4*)xp;
    for (int e = eg; e < nE; e += 8) {
        const int s3 = e >= o3, s2 = e >= o2, s1 = e >= o1;
        const int sg = s1 + s2 + s3;
        const int sub = e - (s3 ? o3 : (s2 ? o2 : (s1 ? o1 : 0)));
        const int j = elist[sg][sub];
        const float p = __expf(fmaf(si + sJ[j * HEADS + h], scale, -m));
        const float4 xv = xp4[j * (FDIM / 4) + h * (OUT_DIM / 4) + d4];
        ax = fmaf(p, xv.x, ax);
        ay = fmaf(p, xv.y, ay);
        az = fmaf(p, xv.z, az);
        aw = fmaf(p, xv.w, aw);
    }
#pragma unroll
    for (int off = 8; off < 64; off <<= 1) {
        ax += __shfl_xor(ax, off);
        ay += __shfl_xor(ay, off);
        az += __shfl_xor(az, off);
        aw += __shfl_xor(aw, off);
    }
    if (eg == 0) {
        const float inv = 1.0f / Z;
        float4 o;
        o.x = ax * inv; o.y = ay * inv; o.z = az * inv; o.w = aw * inv;
        ((float4*)out)[i * (FDIM / 4) + h * (OUT_DIM / 4) + d4] = o;
    }
}

extern "C" void kernel_launch(void* const* d_in, const int* in_sizes, int n_in,
                              void* d_out, int out_size, void* d_ws, size_t ws_size,
                              hipStream_t stream) {
    const float* x   = (const float*)d_in[0];
    const float* adj = (const float*)d_in[1];
    const float* W   = (const float*)d_in[2];
    const float* a   = (const float*)d_in[3];
    float* out = (float*)d_out;

    float* xp = (float*)d_ws;                    // 4096*128 f32 = 2 MB
    float* sI = xp + N_NODES * FDIM;             // 64 KB
    float* sJ = sI + N_NODES * HEADS;            // 64 KB

    gat_proj<<<N_NODES / K1_ROWS, 256, 0, stream>>>(x, W, a, xp, sI, sJ);
    gat_agg<<<N_NODES, 256, 0, stream>>>(adj, xp, sI, sJ, out);
}